// Round 4
// baseline (114.792 us; speedup 1.0000x reference)
//
#include <hip/hip_runtime.h>

// PastFutureContext: B=8, N=1024, d=h=512 — bf16 MFMA, 2-phase double-buffered LDS.
// Math: out = sp_i*(trilW @ GaT^T) + sf_i*(triuW @ GcT^T) + Gb, where
//   W[b]    = proj[b] @ F[b]^T        (proj = F@W1^T + b1)
//   GacT[b] = [W2a;W2c] @ F[b]^T * sm_j
//   Gb      = F @ W2b^T + b2   — written straight into out (f32); tri does RMW.
// K-loop (T3 minimum 2-phase): prologue STAGE(buf0); barrier;
//   loop { STAGE(buf^1, k+1); ds_read+MFMA buf[cur]; barrier; } — load latency
//   hides under compute instead of being drained cold every step.

constexpr int BATCH = 8;
constexpr int SEQ   = 1024;
constexpr int DIM   = 512;
constexpr int HID   = 512;

typedef __bf16 bf16_t;
typedef bf16_t bf16x8 __attribute__((ext_vector_type(8)));
typedef float  f32x4  __attribute__((ext_vector_type(4)));
typedef float  f4     __attribute__((ext_vector_type(4)));

typedef __attribute__((address_space(1))) void gv_t;
typedef __attribute__((address_space(3))) void lv_t;

__device__ __forceinline__ void gload16(const bf16_t* g, bf16_t* l) {
  __builtin_amdgcn_global_load_lds((gv_t*)g, (lv_t*)l, 16, 0, 0);
}

// Stage a [ROWS x 32] bf16 tile (row-major, leading dim ld) into linear LDS.
// Lane l fetches row s*16+l/4, col (l%4)*8; HW writes LDS at base+16B*l.
template <int ROWS>
__device__ __forceinline__ void stage(const bf16_t* g, int ld, bf16_t* lds,
                                      int w, int lane) {
  const int r0 = lane >> 2;
  const int k  = (lane & 3) * 8;
#pragma unroll
  for (int i = 0; i < ROWS / 64; ++i) {
    const int s = w * (ROWS / 64) + i;
    gload16(g + (size_t)(s * 16 + r0) * ld + k, lds + s * 512);
  }
}

// ---- S0: parallel scales ----------------------------------------------------
__global__ __launch_bounds__(1024) void scales_kernel(
    const int* __restrict__ smask, float* __restrict__ sp, float* __restrict__ sf) {
  const int b = blockIdx.x, t = threadIdx.x;
  const int v = smask[b * SEQ + t];
  int x = v;
#pragma unroll
  for (int o = 1; o < 64; o <<= 1) {
    int y = __shfl_up(x, o, 64);
    if ((t & 63) >= o) x += y;
  }
  __shared__ int wsum[16], wpre[17];
  if ((t & 63) == 63) wsum[t >> 6] = x;
  __syncthreads();
  if (t == 0) { int c = 0; for (int w = 0; w < 16; ++w) { wpre[w] = c; c += wsum[w]; } wpre[16] = c; }
  __syncthreads();
  const int inc = x + wpre[t >> 6];
  const float P  = (float)(inc - v);
  const float Fu = (float)(wpre[16] - inc);
  sp[b * SEQ + t] = v ? 1.f / (P  + 1e-8f) : 0.f;
  sf[b * SEQ + t] = v ? 1.f / (Fu + 1e-8f) : 0.f;
}

// ---- S1a: F -> bf16 ----------------------------------------------------------
__global__ void cvt_kernel(const float* __restrict__ in, bf16_t* __restrict__ out, int n8) {
  const int i = blockIdx.x * blockDim.x + threadIdx.x;
  if (i >= n8) return;
  const f4* p = (const f4*)(in + (size_t)i * 8);
  f4 v0 = p[0], v1 = p[1];
  bf16x8 o;
  o[0] = (bf16_t)v0[0]; o[1] = (bf16_t)v0[1]; o[2] = (bf16_t)v0[2]; o[3] = (bf16_t)v0[3];
  o[4] = (bf16_t)v1[0]; o[5] = (bf16_t)v1[1]; o[6] = (bf16_t)v1[2]; o[7] = (bf16_t)v1[3];
  *(bf16x8*)(out + (size_t)i * 8) = o;
}

// ---- S1b: weights -> bf16, restacked ----------------------------------------
__global__ __launch_bounds__(256) void prepw_kernel(
    const float* __restrict__ W1, const float* __restrict__ W2,
    bf16_t* __restrict__ Wpg, bf16_t* __restrict__ W2ac) {
  const int idx = blockIdx.x * 256 + threadIdx.x;
  const int r = idx >> 6, c8 = (idx & 63) * 8;
  const float* src;
  bf16_t* dst;
  if (r < 512)        { src = W1 + (size_t)r * 512 + c8;                    dst = Wpg  + (size_t)r * 512 + c8; }
  else if (r < 1024)  { src = W2 + (size_t)(r - 512) * 1536 + 512 + c8;     dst = Wpg  + (size_t)r * 512 + c8; }
  else if (r < 1536)  { src = W2 + (size_t)(r - 1024) * 1536 + c8;          dst = W2ac + (size_t)(r - 1024) * 512 + c8; }
  else                { src = W2 + (size_t)(r - 1536) * 1536 + 1024 + c8;   dst = W2ac + (size_t)(r - 1024) * 512 + c8; }
  f4 v0 = *(const f4*)src, v1 = *(const f4*)(src + 4);
  bf16x8 o;
  o[0] = (bf16_t)v0[0]; o[1] = (bf16_t)v0[1]; o[2] = (bf16_t)v0[2]; o[3] = (bf16_t)v0[3];
  o[4] = (bf16_t)v1[0]; o[5] = (bf16_t)v1[1]; o[6] = (bf16_t)v1[2]; o[7] = (bf16_t)v1[3];
  *(bf16x8*)dst = o;
}

// ---- double-buffered 128x128 GEMM core ---------------------------------------
__device__ __forceinline__ void gemm_db(
    const bf16_t* __restrict__ A, int lda, const bf16_t* __restrict__ Bt, int ldb,
    int K, bf16_t (*As)[128 * 32], bf16_t (*Bs)[128 * 32], f32x4 acc[4][4],
    int w, int lane, int fr, int fk, int mw, int nw) {
  stage<128>(A, lda, As[0], w, lane);
  stage<128>(Bt, ldb, Bs[0], w, lane);
  __syncthreads();
  for (int k0 = 0; k0 < K; k0 += 32) {
    const int cur = (k0 >> 5) & 1;
    if (k0 + 32 < K) {
      stage<128>(A + k0 + 32, lda, As[cur ^ 1], w, lane);
      stage<128>(Bt + k0 + 32, ldb, Bs[cur ^ 1], w, lane);
    }
    bf16x8 a[4], b[4];
#pragma unroll
    for (int s = 0; s < 4; ++s) a[s] = *(const bf16x8*)&As[cur][(mw + s * 16 + fr) * 32 + fk];
#pragma unroll
    for (int t = 0; t < 4; ++t) b[t] = *(const bf16x8*)&Bs[cur][(nw + t * 16 + fr) * 32 + fk];
#pragma unroll
    for (int s = 0; s < 4; ++s)
#pragma unroll
      for (int t = 0; t < 4; ++t)
        acc[s][t] = __builtin_amdgcn_mfma_f32_16x16x32_bf16(a[s], b[t], acc[s][t], 0, 0, 0);
    __syncthreads();
  }
}

#define TILE_IDS                                  \
  const int tid = threadIdx.x;                    \
  const int w = tid >> 6, lane = tid & 63;        \
  const int fr = lane & 15, fk = (lane >> 4) * 8; \
  const int mw = (w >> 1) * 64, nw = (w & 1) * 64;\
  const int cr = (lane >> 4) * 4, cc = lane & 15;

// ---- S2: [proj | Gb] = F @ [W1;W2b]^T + [b1;b2]; Gb goes straight to out -----
__global__ __launch_bounds__(256) void pg_mfma(
    const bf16_t* __restrict__ Fbf, const bf16_t* __restrict__ Wpg,
    const float* __restrict__ b1, const float* __restrict__ b2,
    bf16_t* __restrict__ projbf, float* __restrict__ out) {
  __shared__ bf16_t As[2][128 * 32], Bs[2][128 * 32];
  TILE_IDS
  const int m0 = blockIdx.y * 128, n0 = blockIdx.x * 128;
  f32x4 acc[4][4] = {};
  gemm_db(Fbf + (size_t)m0 * DIM, DIM, Wpg + (size_t)n0 * DIM, DIM, DIM,
          As, Bs, acc, w, lane, fr, fk, mw, nw);
  if (n0 < 512) {
#pragma unroll
    for (int s = 0; s < 4; ++s)
#pragma unroll
      for (int t = 0; t < 4; ++t) {
        const int col = n0 + nw + t * 16 + cc;
        const float bv = b1[col];
#pragma unroll
        for (int r = 0; r < 4; ++r)
          projbf[(size_t)(m0 + mw + s * 16 + cr + r) * HID + col] = (bf16_t)(acc[s][t][r] + bv);
      }
  } else {
#pragma unroll
    for (int s = 0; s < 4; ++s)
#pragma unroll
      for (int t = 0; t < 4; ++t) {
        const int col = (n0 - 512) + nw + t * 16 + cc;
        const float bv = b2[col];
#pragma unroll
        for (int r = 0; r < 4; ++r)
          out[(size_t)(m0 + mw + s * 16 + cr + r) * HID + col] = acc[s][t][r] + bv;
      }
  }
}

// ---- S3: weight[b] = proj[b] @ F[b]^T ----------------------------------------
__global__ __launch_bounds__(256) void weight_mfma(
    const bf16_t* __restrict__ projbf, const bf16_t* __restrict__ Fbf,
    bf16_t* __restrict__ wbuf, int b0) {
  __shared__ bf16_t As[2][128 * 32], Bs[2][128 * 32];
  TILE_IDS
  const int b = b0 + blockIdx.z;
  const bf16_t* A  = projbf + (size_t)b * SEQ * DIM;
  const bf16_t* Bt = Fbf    + (size_t)b * SEQ * DIM;
  bf16_t* C = wbuf + (size_t)blockIdx.z * SEQ * SEQ;
  const int m0 = blockIdx.y * 128, n0 = blockIdx.x * 128;
  f32x4 acc[4][4] = {};
  gemm_db(A + (size_t)m0 * DIM, DIM, Bt + (size_t)n0 * DIM, DIM, DIM,
          As, Bs, acc, w, lane, fr, fk, mw, nw);
#pragma unroll
  for (int s = 0; s < 4; ++s)
#pragma unroll
    for (int t = 0; t < 4; ++t)
#pragma unroll
      for (int r = 0; r < 4; ++r)
        C[(size_t)(m0 + mw + s * 16 + cr + r) * SEQ + n0 + nw + t * 16 + cc] = (bf16_t)acc[s][t][r];
}

// ---- S4: GacT[b][m][j] = ([W2a;W2c] @ F[b]^T)[m][j] * sm_j -------------------
__global__ __launch_bounds__(256) void gact_mfma(
    const bf16_t* __restrict__ W2ac, const bf16_t* __restrict__ Fbf,
    const int* __restrict__ smask, bf16_t* __restrict__ GacT) {
  __shared__ bf16_t As[2][128 * 32], Bs[2][128 * 32];
  TILE_IDS
  const int b = blockIdx.z;
  const bf16_t* Bt = Fbf + (size_t)b * SEQ * DIM;
  const int m0 = blockIdx.y * 128, n0 = blockIdx.x * 128;
  f32x4 acc[4][4] = {};
  gemm_db(W2ac + (size_t)m0 * DIM, DIM, Bt + (size_t)n0 * DIM, DIM, DIM,
          As, Bs, acc, w, lane, fr, fk, mw, nw);
  bf16_t* C = GacT + (size_t)b * SEQ * SEQ;
#pragma unroll
  for (int s = 0; s < 4; ++s)
#pragma unroll
    for (int t = 0; t < 4; ++t) {
      const int j = n0 + nw + t * 16 + cc;
      const float smj = (float)smask[b * SEQ + j];
#pragma unroll
      for (int r = 0; r < 4; ++r)
        C[(size_t)(m0 + mw + s * 16 + cr + r) * SEQ + j] = (bf16_t)(acc[s][t][r] * smj);
    }
}

// ---- S5: tri — out += sp*(trilW @ GaT^T) + sf*(triuW @ GcT^T) ----------------
__global__ __launch_bounds__(256) void tri_mfma(
    const bf16_t* __restrict__ wbuf, const bf16_t* __restrict__ GacT,
    const float* __restrict__ scaleP, const float* __restrict__ scaleF,
    float* __restrict__ out, int b0) {
  __shared__ bf16_t As[2][128 * 32], BPs[2][64 * 32], BFs[2][64 * 32];
  const int tid = threadIdx.x;
  const int w = tid >> 6, lane = tid & 63;
  const int fr = lane & 15, fk = (lane >> 4) * 8;
  const int mw = (w >> 1) * 64, nw2 = (w & 1) * 32;
  const int cr = (lane >> 4) * 4, cc = lane & 15;
  const int b = b0 + blockIdx.z;
  const bf16_t* A   = wbuf + (size_t)blockIdx.z * SEQ * SEQ;
  const bf16_t* GaT = GacT + (size_t)b * SEQ * SEQ;   // rows 0..511: a, 512..1023: c
  const int i0 = blockIdx.y * 128, n0 = blockIdx.x * 64;
  f32x4 accP[4][2] = {}, accF[4][2] = {};
  // prologue: stage j0 = 0
  stage<128>(A + (size_t)i0 * SEQ, SEQ, As[0], w, lane);
  stage<64>(GaT + (size_t)n0 * SEQ, SEQ, BPs[0], w, lane);            // blkP(0) always true
  if (31 > i0) stage<64>(GaT + (size_t)(512 + n0) * SEQ, SEQ, BFs[0], w, lane);
  __syncthreads();
  for (int j0 = 0; j0 < SEQ; j0 += 32) {
    const int cur = (j0 >> 5) & 1;
    const int jn = j0 + 32;
    if (jn < SEQ) {
      stage<128>(A + (size_t)i0 * SEQ + jn, SEQ, As[cur ^ 1], w, lane);
      if (jn < i0 + 128) stage<64>(GaT + (size_t)n0 * SEQ + jn, SEQ, BPs[cur ^ 1], w, lane);
      if (jn + 31 > i0)  stage<64>(GaT + (size_t)(512 + n0) * SEQ + jn, SEQ, BFs[cur ^ 1], w, lane);
    }
    const bool wP = (j0 < i0 + mw + 64);
    const bool wF = (j0 + 31 > i0 + mw);
    if (wP || wF) {
      bf16x8 bP[2], bF[2];
#pragma unroll
      for (int t = 0; t < 2; ++t) {
        if (wP) bP[t] = *(const bf16x8*)&BPs[cur][(nw2 + t * 16 + fr) * 32 + fk];
        if (wF) bF[t] = *(const bf16x8*)&BFs[cur][(nw2 + t * 16 + fr) * 32 + fk];
      }
#pragma unroll
      for (int s = 0; s < 4; ++s) {
        const int rlo = i0 + mw + s * 16;
        const bool pAny = (j0 < rlo + 15), pFull = (j0 + 31 < rlo);
        const bool fAny = (j0 + 31 > rlo), fFull = (j0 > rlo + 15);
        if (!pAny && !fAny) continue;
        const bf16x8 a = *(const bf16x8*)&As[cur][(mw + s * 16 + fr) * 32 + fk];
        if (pFull) {
#pragma unroll
          for (int t = 0; t < 2; ++t)
            accP[s][t] = __builtin_amdgcn_mfma_f32_16x16x32_bf16(a, bP[t], accP[s][t], 0, 0, 0);
        } else if (pAny) {
          const int cut = (rlo + fr) - (j0 + fk);     // keep e < cut  (j < i)
          bf16x8 ap = a;
#pragma unroll
          for (int e = 0; e < 8; ++e) if (e >= cut) ap[e] = (bf16_t)0.f;
#pragma unroll
          for (int t = 0; t < 2; ++t)
            accP[s][t] = __builtin_amdgcn_mfma_f32_16x16x32_bf16(ap, bP[t], accP[s][t], 0, 0, 0);
        }
        if (fFull) {
#pragma unroll
          for (int t = 0; t < 2; ++t)
            accF[s][t] = __builtin_amdgcn_mfma_f32_16x16x32_bf16(a, bF[t], accF[s][t], 0, 0, 0);
        } else if (fAny) {
          const int cut = (rlo + fr) - (j0 + fk);     // keep e > cut  (j > i)
          bf16x8 af = a;
#pragma unroll
          for (int e = 0; e < 8; ++e) if (e <= cut) af[e] = (bf16_t)0.f;
#pragma unroll
          for (int t = 0; t < 2; ++t)
            accF[s][t] = __builtin_amdgcn_mfma_f32_16x16x32_bf16(af, bF[t], accF[s][t], 0, 0, 0);
        }
      }
    }
    __syncthreads();
  }
#pragma unroll
  for (int s = 0; s < 4; ++s)
#pragma unroll
    for (int r = 0; r < 4; ++r) {
      const int row = i0 + mw + s * 16 + cr + r;
      const float spv = scaleP[b * SEQ + row];
      const float sfv = scaleF[b * SEQ + row];
#pragma unroll
      for (int t = 0; t < 2; ++t) {
        const int col = n0 + nw2 + t * 16 + cc;
        const size_t oi = ((size_t)b * SEQ + row) * HID + col;
        out[oi] = accP[s][t][r] * spv + accF[s][t][r] * sfv + out[oi];  // Gb already in out
      }
    }
}

extern "C" void kernel_launch(void* const* d_in, const int* in_sizes, int n_in,
                              void* d_out, int out_size, void* d_ws, size_t ws_size,
                              hipStream_t stream) {
  const float* F  = (const float*)d_in[0];
  const int*   sm = (const int*)  d_in[1];
  const float* W1 = (const float*)d_in[2];
  const float* b1 = (const float*)d_in[3];
  const float* W2 = (const float*)d_in[4];
  const float* b2 = (const float*)d_in[5];
  float* out = (float*)d_out;

  char* ws = (char*)d_ws;
  size_t off = 0;
  auto take = [&](size_t bytes) -> void* {
    void* p = ws + off;
    off += (bytes + 255) & ~(size_t)255;
    return p;
  };
  bf16_t* Fbf    = (bf16_t*)take((size_t)BATCH * SEQ * DIM * 2);   // 8 MB
  bf16_t* projbf = (bf16_t*)take((size_t)BATCH * SEQ * HID * 2);   // 8 MB
  bf16_t* GacT   = (bf16_t*)take((size_t)BATCH * SEQ * SEQ * 2);   // 16 MB
  bf16_t* Wpg    = (bf16_t*)take((size_t)1024 * 512 * 2);          // 1 MB
  bf16_t* W2ac   = (bf16_t*)take((size_t)1024 * 512 * 2);          // 1 MB
  float*  scaleP = (float*) take((size_t)BATCH * SEQ * 4);
  float*  scaleF = (float*) take((size_t)BATCH * SEQ * 4);

  const size_t wbytes = (size_t)SEQ * SEQ * 2;
  int chunk = (ws_size > off) ? (int)((ws_size - off) / wbytes) : 1;
  if (chunk > BATCH) chunk = BATCH;
  if (chunk < 1) chunk = 1;
  bf16_t* wbuf = (bf16_t*)(ws + off);

  scales_kernel<<<dim3(BATCH), dim3(1024), 0, stream>>>(sm, scaleP, scaleF);
  cvt_kernel<<<dim3(BATCH * SEQ * DIM / 8 / 256), dim3(256), 0, stream>>>(F, Fbf, BATCH * SEQ * DIM / 8);
  prepw_kernel<<<dim3(512), dim3(256), 0, stream>>>(W1, W2, Wpg, W2ac);

  pg_mfma<<<dim3(1024 / 128, BATCH * SEQ / 128), dim3(256), 0, stream>>>(
      Fbf, Wpg, b1, b2, projbf, out);
  gact_mfma<<<dim3(SEQ / 128, SEQ / 128, BATCH), dim3(256), 0, stream>>>(
      W2ac, Fbf, sm, GacT);
  for (int b0 = 0; b0 < BATCH; b0 += chunk) {
    const int nb = (BATCH - b0 < chunk) ? (BATCH - b0) : chunk;
    weight_mfma<<<dim3(SEQ / 128, SEQ / 128, nb), dim3(256), 0, stream>>>(projbf, Fbf, wbuf, b0);
    tri_mfma<<<dim3(HID / 64, SEQ / 128, nb), dim3(256), 0, stream>>>(
        wbuf, GacT, scaleP, scaleF, out, b0);
  }
}